// Round 10
// baseline (2935.999 us; speedup 1.0000x reference)
//
#include <hip/hip_runtime.h>
#include <stdint.h>

typedef uint16_t u16;
typedef unsigned long long u64;
typedef __attribute__((ext_vector_type(8))) short short8;   // 8 x bf16 bits (4 VGPRs)
typedef __attribute__((ext_vector_type(4))) float f32x4;
typedef __attribute__((ext_vector_type(2))) unsigned long long ull2;  // 16B record frag

#define SCOPE __HIP_MEMORY_SCOPE_AGENT
#define FSTRIDE 64   // ints per edge flag line (256B, exclusive per edge)

static __device__ __forceinline__ float bf2f(u16 b) {
  union { uint32_t u; float f; } x; x.u = ((uint32_t)b) << 16; return x.f;
}
static __device__ __forceinline__ u16 f2bf(float f) {
  union { float f; uint32_t u; } x; x.f = f;
  uint32_t u = x.u;
  u += 0x7fffu + ((u >> 16) & 1u);   // RTNE
  return (u16)(u >> 16);
}
static __device__ __forceinline__ float sigm(float x) {
  x = fminf(30.f, fmaxf(-30.f, x));
  return __builtin_amdgcn_rcpf(1.f + __expf(-x));
}
static __device__ __forceinline__ float tanhf_(float x) {
  x = fminf(15.f, fmaxf(-15.f, x));
  return 1.f - 2.f * __builtin_amdgcn_rcpf(1.f + __expf(2.f * x));
}
// LDS-only barrier: does NOT drain vmcnt.
static __device__ __forceinline__ void lds_barrier() {
  asm volatile("s_waitcnt lgkmcnt(0)\n\ts_barrier" ::: "memory");
}

// R10: payload OFF the fine-grained coherence path. R9 confirmed dur ~= sc1
// bytes / 280GB/s (fine-grained agent-scope write-through + L2-bypass loads;
// WRITE_SIZE showed 2x partial-line inflation). Records are now PLAIN cached
// dwordx4 ops; visibility via once-per-chunk __threadfence() (agent fence =
// buffer_wbl2 sc1 + waitcnt + buffer_inv): producer syncthreads -> tid0 fence
// (bulk L2 writeback) -> sc1 flag; consumer polls flag -> wave0 fence (L1/L2
// inv, caches are CU/XCD-shared so one wave covers the WG) -> barrier -> plain
// cached loads. Flags remain sc1 atomics. CH=8 amortizes the fence.
// Two layers fused per WG (R9): 128 WGs = 32 pairs x 4 batch chunks.
// MFMA 16x16x32 bf16 layouts (m89-verified):
//   A-frag: lane holds A[m=lane&15][k=(lane>>4)*8+j]
//   B-frag: lane holds B[k=(lane>>4)*8+j][n=lane&15]  (W row-major (N,K))
//   C/D: reg p -> (row=(lane>>4)*4+p, col=lane&15)
template <int CH>
__global__ __launch_bounds__(256, 1) void gru_pipeline(
    const void* ctx_,
    const void* eWih0_, const void* eWih_, const void* eWhh_,
    const void* ebih_,  const void* ebhh_,
    const void* dWih0_, const void* dWih_, const void* dWhh_,
    const void* dbih_,  const void* dbhh_,
    const void* Wo_,    const void* bo_,   void* out_,
    int* __restrict__ pflag, int* __restrict__ cflag,
    u64* __restrict__ xbuf, int R)
{
  const int tid  = threadIdx.x;
  const int lane = tid & 63;
  const int wid  = tid >> 6;
  const int rt   = wid >> 1;      // row-tile (16 batch rows each)
  const int cs   = wid & 1;       // gate-col half
  const int lo   = lane & 15;
  const int hi   = lane >> 4;
  const int blk  = blockIdx.x;
  const int P    = blk >> 2;      // layer pair 0..31  (layers 2P, 2P+1)
  const int g    = blk & 3;       // batch chunk
  const int LA   = 2 * P;
  const int LB   = 2 * P + 1;
  const int NKCA = (P == 0) ? 4 : 2;   // layer A k-chunks (K=128 for layer 0)
  const int RM   = R - 1;              // R is a power of two
  const int RC   = (R / CH) > 0 ? (R / CH) : 1;
  const int NCH  = 512 / CH;

  __shared__ __align__(16) u16 hbA[2][32 * 72];
  __shared__ __align__(16) u16 hbB[2][32 * 72];
  __shared__ __align__(16) u16 xstA[2][32 * 72];
  __shared__ __align__(16) u16 xstB[32 * 72];
  __shared__ int s_cnt;
  if (tid == 0) s_cnt = 0;
  for (int i = tid; i < 32 * 72; i += 256) {
    hbA[0][i] = 0; hbA[1][i] = 0; hbB[0][i] = 0; hbB[1][i] = 0;
    xstA[0][i] = 0; xstA[1][i] = 0; xstB[i] = 0;
  }
  __syncthreads();
  {  // dtype probe: even u16s of enc_bih
    u16 v = ((const u16*)ebih_)[2 * tid];
    int e = (v >> 7) & 0xFF;
    if (e >= 100 && e <= 126) atomicAdd(&s_cnt, 1);
  }
  __syncthreads();
  const bool bf = (s_cnt >= 128);   // true: bf16 tensors; false: fp32

  auto ld8 = [&](const void* p, int idx) -> short8 {
    if (bf) return *(const short8*)((const u16*)p + idx);
    const float* f = (const float*)p + idx;
    short8 r;
#pragma unroll
    for (int j = 0; j < 8; ++j) r[j] = (short)f2bf(f[j]);
    return r;
  };
  auto ld1 = [&](const void* p, int idx) -> float {
    return bf ? bf2f(((const u16*)p)[idx]) : ((const float*)p)[idx];
  };

  int T[6];
  T[0] = 2*cs; T[1] = 2*cs+1; T[2] = 4+2*cs; T[3] = 5+2*cs; T[4] = 8+2*cs; T[5] = 9+2*cs;

  short8 zf8 = {0,0,0,0,0,0,0,0};
  short8 whA[6][2], wiA[6][4];     // layer A (wiA[.][2..3] only for P==0)
  short8 whB[6][2], wiB[6][2];     // layer B
  short8 wo[2][2];                 // pair-31 only
  float  bov[2] = {0.f, 0.f};
  float brzA[4], binA[2], bhnA[2];
  float brzB[4], binB[2], bhnB[2];
#pragma unroll
  for (int a = 0; a < 6; ++a) {
    whA[a][0]=zf8; whA[a][1]=zf8; whB[a][0]=zf8; whB[a][1]=zf8;
    wiB[a][0]=zf8; wiB[a][1]=zf8;
#pragma unroll
    for (int b = 0; b < 4; ++b) wiA[a][b]=zf8;
  }
  wo[0][0]=wo[0][1]=wo[1][0]=wo[1][1]=zf8;

  auto load_phase = [&](int ph) {
    const void* WH = ph ? dWhh_ : eWhh_;
    const void* WIs = ph ? dWih_ : eWih_;
    const void* WI0 = ph ? dWih0_ : eWih0_;
    const void* bi = ph ? dbih_ : ebih_;
    const void* bh = ph ? dbhh_ : ebhh_;
    const void* WIA = (LA == 0) ? WI0 : WIs;
    const int  iA   = (LA == 0) ? 0 : (LA - 1) * 192 * 64;
    const int  KINA = (LA == 0) ? 128 : 64;
#pragma unroll
    for (int ti = 0; ti < 6; ++ti) {
#pragma unroll
      for (int kc = 0; kc < 2; ++kc) {
        whA[ti][kc] = ld8(WH, LA*192*64 + (T[ti]*16 + lo)*64 + kc*32 + hi*8);
        whB[ti][kc] = ld8(WH, LB*192*64 + (T[ti]*16 + lo)*64 + kc*32 + hi*8);
        wiB[ti][kc] = ld8(WIs, LA*192*64 + (T[ti]*16 + lo)*64 + kc*32 + hi*8); // Wih[LB-1]=Wih[LA]
      }
#pragma unroll
      for (int kc = 0; kc < 4; ++kc)
        if (kc < NKCA)
          wiA[ti][kc] = ld8(WIA, iA + (T[ti]*16 + lo)*KINA + kc*32 + hi*8);
    }
#pragma unroll
    for (int q = 0; q < 4; ++q) {
      brzA[q] = ld1(bi, LA*192 + T[q]*16 + lo) + ld1(bh, LA*192 + T[q]*16 + lo);
      brzB[q] = ld1(bi, LB*192 + T[q]*16 + lo) + ld1(bh, LB*192 + T[q]*16 + lo);
    }
#pragma unroll
    for (int q = 0; q < 2; ++q) {
      binA[q] = ld1(bi, LA*192 + T[4+q]*16 + lo);
      bhnA[q] = ld1(bh, LA*192 + T[4+q]*16 + lo);
      binB[q] = ld1(bi, LB*192 + T[4+q]*16 + lo);
      bhnB[q] = ld1(bh, LB*192 + T[4+q]*16 + lo);
    }
  };
  load_phase(0);
  if (P == 31) {
#pragma unroll
    for (int ct = 0; ct < 2; ++ct) {
      int n = 32*wid + 16*ct + lo;
#pragma unroll
      for (int kc = 0; kc < 2; ++kc)
        wo[ct][kc] = ld8(Wo_, n*64 + kc*32 + hi*8);
      bov[ct] = ld1(bo_, n);
    }
  }

  auto do_proj = [&](int tprev, const u16* hs) {
    f32x4 pacc[2][2];
#pragma unroll
    for (int rtl = 0; rtl < 2; ++rtl)
#pragma unroll
      for (int ct = 0; ct < 2; ++ct) {
        float v = bov[ct]; f32x4 tv = {v, v, v, v}; pacc[rtl][ct] = tv;
      }
#pragma unroll
    for (int kc = 0; kc < 2; ++kc) {
      short8 hA0 = *(const short8*)(hs + (0*16 + lo)*72 + kc*32 + hi*8);
      short8 hA1 = *(const short8*)(hs + (1*16 + lo)*72 + kc*32 + hi*8);
      pacc[0][0] = __builtin_amdgcn_mfma_f32_16x16x32_bf16(hA0, wo[0][kc], pacc[0][0], 0, 0, 0);
      pacc[0][1] = __builtin_amdgcn_mfma_f32_16x16x32_bf16(hA0, wo[1][kc], pacc[0][1], 0, 0, 0);
      pacc[1][0] = __builtin_amdgcn_mfma_f32_16x16x32_bf16(hA1, wo[0][kc], pacc[1][0], 0, 0, 0);
      pacc[1][1] = __builtin_amdgcn_mfma_f32_16x16x32_bf16(hA1, wo[1][kc], pacc[1][1], 0, 0, 0);
    }
#pragma unroll
    for (int rtl = 0; rtl < 2; ++rtl)
#pragma unroll
      for (int ct = 0; ct < 2; ++ct) {
        int n = 32*wid + 16*ct + lo;
#pragma unroll
        for (int p = 0; p < 4; ++p) {
          int b = 32*g + rtl*16 + hi*4 + p;
          size_t idx = ((size_t)b * 256 + (tprev - 256)) * 128 + n;
          float v = fminf(64.f, fmaxf(-64.f, pacc[rtl][ct][p]));
          if (bf) ((u16*)out_)[idx] = f2bf(v);
          else    ((float*)out_)[idx] = v;
        }
      }
  };

  float hprevA[2][4], hprevB[2][4];
#pragma unroll
  for (int q = 0; q < 2; ++q)
#pragma unroll
    for (int p = 0; p < 4; ++p) { hprevA[q][p] = 0.f; hprevB[q][p] = 0.f; }

  const int brow = 32*g + rt*16 + lo;

  const int eIn  = (P > 0 ? P - 1 : 0) * 4 + g;   // deref'd only when P>0
  const int eOut = (P < 31 ? P : 30) * 4 + g;     // deref'd only when P<31
  const u64* recin  = xbuf + (size_t)eIn  * R * 512;
  u64*       recout = xbuf + (size_t)eOut * R * 512;
  int* fin   = pflag + eIn  * FSTRIDE;            // single flag per edge
  int* fout  = pflag + eOut * FSTRIDE;
  int* cself = cflag + (P * 4 + g) * FSTRIDE;
  int* cnext = cflag + ((P < 31 ? P + 1 : 31) * 4 + g) * FSTRIDE;

  int budget = 1 << 22;   // anti-hang

  const int srow = (tid >> 7) * 16 + ((tid >> 4) & 3) * 4;
  const int scol = ((tid >> 6) & 1) * 32 + (tid & 15);

  __syncthreads();

  for (int k = 0; k < NCH; ++k) {
    const int t0 = k * CH;
    if (t0 == 256) load_phase(1);

    // ---- once-per-chunk sync: wave 0 polls sc1 flags; ONE __threadfence()
    // (buffer_inv) makes the producers' bulk-written records visible to the
    // whole WG (L1/L2 are CU/XCD-shared).
    if (wid == 0) {
      bool need_fence = false;
      if (P < 31 && k >= RC) {
        while (budget > 0) {
          int v = __hip_atomic_load(cnext, __ATOMIC_RELAXED, SCOPE);
          if (v >= k + 1 - RC) break;
          --budget; __builtin_amdgcn_s_sleep(2);
        }
      }
      if (P > 0) {
        while (budget > 0) {
          int v = __hip_atomic_load(fin, __ATOMIC_RELAXED, SCOPE);
          if (v >= k + 1) break;
          --budget; __builtin_amdgcn_s_sleep(2);
        }
        need_fence = true;
      }
      if (need_fence) __threadfence();   // agent fence: wbl2 + waitcnt + inv
    }
    __syncthreads();   // Bc: caches invalidated; chunk-k records readable

    // ---- prime the whole chunk's record loads (plain cached dwordx4)
    ull2 pr[CH];
    if (P > 0) {
#pragma unroll
      for (int j = 0; j < CH; ++j)
        pr[j] = *(const ull2*)(recin + (size_t)((t0 + j) & RM) * 512 + tid * 2);
    }

#pragma unroll 1
    for (int tt = 0; tt < CH; ++tt) {
      const int t = t0 + tt;

      // ---- stage x_t for layer A -> xstA[t&1]
      if (P > 0) {
        u16* xd = xstA[t & 1];
        u64 a = pr[tt].x, b = pr[tt].y;
#pragma unroll
        for (int p = 0; p < 4; ++p) {
          xd[(srow + p) * 72 + scol]      = (u16)(a >> (16 * p));
          xd[(srow + p) * 72 + scol + 16] = (u16)(b >> (16 * p));
        }
      }

      lds_barrier();   // B1: xstA(t), hbA(t-1), hbB(t-1) visible

      // ---- pair 31: projection of step t-1 (h63_{t-1} in hbB[(t+1)&1])
      if (P == 31 && t >= 257) do_proj(t - 1, hbB[(t + 1) & 1]);

      // ================= layer A =================
      f32x4 acc_rz[4], acc_in[2], acc_hn[2];
#pragma unroll
      for (int q = 0; q < 4; ++q) { float v = brzA[q]; f32x4 tv = {v,v,v,v}; acc_rz[q] = tv; }
#pragma unroll
      for (int q = 0; q < 2; ++q) { float v = binA[q]; f32x4 tv = {v,v,v,v}; acc_in[q] = tv;
                                    float w = bhnA[q]; f32x4 tw = {w,w,w,w}; acc_hn[q] = tw; }
      const u16* hsA = hbA[(t + 1) & 1];
#pragma unroll
      for (int kc = 0; kc < 2; ++kc) {
        short8 hA = *(const short8*)(hsA + (rt*16 + lo)*72 + kc*32 + hi*8);
        acc_rz[0] = __builtin_amdgcn_mfma_f32_16x16x32_bf16(hA, whA[0][kc], acc_rz[0], 0, 0, 0);
        acc_rz[1] = __builtin_amdgcn_mfma_f32_16x16x32_bf16(hA, whA[1][kc], acc_rz[1], 0, 0, 0);
        acc_rz[2] = __builtin_amdgcn_mfma_f32_16x16x32_bf16(hA, whA[2][kc], acc_rz[2], 0, 0, 0);
        acc_rz[3] = __builtin_amdgcn_mfma_f32_16x16x32_bf16(hA, whA[3][kc], acc_rz[3], 0, 0, 0);
        acc_hn[0] = __builtin_amdgcn_mfma_f32_16x16x32_bf16(hA, whA[4][kc], acc_hn[0], 0, 0, 0);
        acc_hn[1] = __builtin_amdgcn_mfma_f32_16x16x32_bf16(hA, whA[5][kc], acc_hn[1], 0, 0, 0);
      }
      short8 xfA[4] = {zf8, zf8, zf8, zf8};
      if (P > 0) {
        const u16* xs = xstA[t & 1];
#pragma unroll
        for (int kc = 0; kc < 2; ++kc)
          xfA[kc] = *(const short8*)(xs + (rt*16 + lo)*72 + kc*32 + hi*8);
      } else {
        int tx = (t < 256) ? t : ((t == 256) ? 0 : t - 257);
#pragma unroll
        for (int kc = 0; kc < 4; ++kc)
          xfA[kc] = ld8(ctx_, (brow * 256 + tx) * 128 + kc*32 + hi*8);
      }
      if (!(P == 0 && t == 256)) {
#pragma unroll
        for (int kc = 0; kc < 4; ++kc) {
          if (kc < NKCA) {
            acc_rz[0] = __builtin_amdgcn_mfma_f32_16x16x32_bf16(xfA[kc], wiA[0][kc], acc_rz[0], 0, 0, 0);
            acc_rz[1] = __builtin_amdgcn_mfma_f32_16x16x32_bf16(xfA[kc], wiA[1][kc], acc_rz[1], 0, 0, 0);
            acc_rz[2] = __builtin_amdgcn_mfma_f32_16x16x32_bf16(xfA[kc], wiA[2][kc], acc_rz[2], 0, 0, 0);
            acc_rz[3] = __builtin_amdgcn_mfma_f32_16x16x32_bf16(xfA[kc], wiA[3][kc], acc_rz[3], 0, 0, 0);
            acc_in[0] = __builtin_amdgcn_mfma_f32_16x16x32_bf16(xfA[kc], wiA[4][kc], acc_in[0], 0, 0, 0);
            acc_in[1] = __builtin_amdgcn_mfma_f32_16x16x32_bf16(xfA[kc], wiA[5][kc], acc_in[1], 0, 0, 0);
          }
        }
      }
      u16 hAb[2][4];
#pragma unroll
      for (int q = 0; q < 2; ++q)
#pragma unroll
        for (int p = 0; p < 4; ++p) {
          float r = sigm(acc_rz[q][p]);
          float z = sigm(acc_rz[2 + q][p]);
          float n = tanhf_(acc_in[q][p] + r * acc_hn[q][p]);
          float h = n + z * (hprevA[q][p] - n);
          h = fminf(1.f, fmaxf(-1.f, h));
          hprevA[q][p] = h;
          hAb[q][p] = f2bf(h);
        }
      {  // h_A -> hbA[t&1] (recurrence) and xstB (x for layer B)
        u16* hd = hbA[t & 1];
#pragma unroll
        for (int q = 0; q < 2; ++q)
#pragma unroll
          for (int p = 0; p < 4; ++p) {
            int ridx = (rt*16 + hi*4 + p) * 72 + cs*32 + q*16 + lo;
            hd[ridx] = hAb[q][p];
            xstB[ridx] = hAb[q][p];
          }
      }

      lds_barrier();   // B2: xstB(t) visible

      // ================= layer B =================
#pragma unroll
      for (int q = 0; q < 4; ++q) { float v = brzB[q]; f32x4 tv = {v,v,v,v}; acc_rz[q] = tv; }
#pragma unroll
      for (int q = 0; q < 2; ++q) { float v = binB[q]; f32x4 tv = {v,v,v,v}; acc_in[q] = tv;
                                    float w = bhnB[q]; f32x4 tw = {w,w,w,w}; acc_hn[q] = tw; }
      const u16* hsB = hbB[(t + 1) & 1];
#pragma unroll
      for (int kc = 0; kc < 2; ++kc) {
        short8 hB = *(const short8*)(hsB + (rt*16 + lo)*72 + kc*32 + hi*8);
        short8 xB = *(const short8*)(xstB + (rt*16 + lo)*72 + kc*32 + hi*8);
        acc_rz[0] = __builtin_amdgcn_mfma_f32_16x16x32_bf16(hB, whB[0][kc], acc_rz[0], 0, 0, 0);
        acc_rz[1] = __builtin_amdgcn_mfma_f32_16x16x32_bf16(hB, whB[1][kc], acc_rz[1], 0, 0, 0);
        acc_rz[2] = __builtin_amdgcn_mfma_f32_16x16x32_bf16(hB, whB[2][kc], acc_rz[2], 0, 0, 0);
        acc_rz[3] = __builtin_amdgcn_mfma_f32_16x16x32_bf16(hB, whB[3][kc], acc_rz[3], 0, 0, 0);
        acc_hn[0] = __builtin_amdgcn_mfma_f32_16x16x32_bf16(hB, whB[4][kc], acc_hn[0], 0, 0, 0);
        acc_hn[1] = __builtin_amdgcn_mfma_f32_16x16x32_bf16(hB, whB[5][kc], acc_hn[1], 0, 0, 0);
        acc_rz[0] = __builtin_amdgcn_mfma_f32_16x16x32_bf16(xB, wiB[0][kc], acc_rz[0], 0, 0, 0);
        acc_rz[1] = __builtin_amdgcn_mfma_f32_16x16x32_bf16(xB, wiB[1][kc], acc_rz[1], 0, 0, 0);
        acc_rz[2] = __builtin_amdgcn_mfma_f32_16x16x32_bf16(xB, wiB[2][kc], acc_rz[2], 0, 0, 0);
        acc_rz[3] = __builtin_amdgcn_mfma_f32_16x16x32_bf16(xB, wiB[3][kc], acc_rz[3], 0, 0, 0);
        acc_in[0] = __builtin_amdgcn_mfma_f32_16x16x32_bf16(xB, wiB[4][kc], acc_in[0], 0, 0, 0);
        acc_in[1] = __builtin_amdgcn_mfma_f32_16x16x32_bf16(xB, wiB[5][kc], acc_in[1], 0, 0, 0);
      }
      u16 hBb[2][4];
#pragma unroll
      for (int q = 0; q < 2; ++q)
#pragma unroll
        for (int p = 0; p < 4; ++p) {
          float r = sigm(acc_rz[q][p]);
          float z = sigm(acc_rz[2 + q][p]);
          float n = tanhf_(acc_in[q][p] + r * acc_hn[q][p]);
          float h = n + z * (hprevB[q][p] - n);
          h = fminf(1.f, fmaxf(-1.f, h));
          hprevB[q][p] = h;
          hBb[q][p] = f2bf(h);
        }
      {
        u16* hd = hbB[t & 1];
#pragma unroll
        for (int q = 0; q < 2; ++q)
#pragma unroll
          for (int p = 0; p < 4; ++p)
            hd[(rt*16 + hi*4 + p) * 72 + cs*32 + q*16 + lo] = hBb[q][p];
      }
      if (P < 31) {   // record h_B for the next pair (PLAIN cached 16B store)
        ull2 rv;
        rv.x = (u64)hBb[0][0] | ((u64)hBb[0][1] << 16) | ((u64)hBb[0][2] << 32) | ((u64)hBb[0][3] << 48);
        rv.y = (u64)hBb[1][0] | ((u64)hBb[1][1] << 16) | ((u64)hBb[1][2] << 32) | ((u64)hBb[1][3] << 48);
        *(ull2*)(recout + (size_t)(t & RM) * 512 + tid * 2) = rv;
      }
    }

    // ---- chunk-end: barrier drains all waves' stores into local L2; tid0's
    // __threadfence() (wbl2 sc1 + waitcnt) pushes them to the coherence point,
    // then the sc1 flag publishes.
    __syncthreads();
    if (tid == 0) {
      if (P < 31) { __threadfence(); __hip_atomic_store(fout,  k + 1, __ATOMIC_RELAXED, SCOPE); }
      if (P > 0)  __hip_atomic_store(cself, k + 1, __ATOMIC_RELAXED, SCOPE);
    }
  }

  // ---- epilogue: projection of the final step (t = 511)
  lds_barrier();
  if (P == 31) do_proj(511, hbB[1]);
}

extern "C" void kernel_launch(void* const* d_in, const int* in_sizes, int n_in,
                              void* d_out, int out_size, void* d_ws, size_t ws_size,
                              hipStream_t stream)
{
  char* ws = (char*)d_ws;
  int* pflag = (int*)ws;                    // per-edge 256B flag lines
  int* cflag = (int*)(ws + 65536);
  u64* xbuf  = (u64*)(ws + 262144);         // handoff ring

  size_t avail = (ws_size > 262144) ? ws_size - 262144 : 0;
  size_t per_slot = (size_t)31 * 4 * 4096;  // one ring step across all 31x4 edges
  int R = 1;
  for (int r = 128; r >= 1; r >>= 1)
    if ((size_t)r * per_slot <= avail) { R = r; break; }

  hipMemsetAsync(ws, 0, 262144, stream);    // zero flags every launch

#define LAUNCH(CHV)                                                        \
  gru_pipeline<CHV><<<128, 256, 0, stream>>>(                              \
      d_in[0], d_in[1], d_in[2], d_in[3], d_in[4], d_in[5],                \
      d_in[6], d_in[7], d_in[8], d_in[9], d_in[10], d_in[11], d_in[12],    \
      d_out, pflag, cflag, xbuf, R)

  if      (R >= 16) LAUNCH(8);
  else if (R >= 8)  LAUNCH(4);
  else if (R >= 4)  LAUNCH(2);
  else              LAUNCH(1);
#undef LAUNCH
  (void)in_sizes; (void)n_in; (void)out_size;
}